// Round 4
// baseline (7345.763 us; speedup 1.0000x reference)
//
#include <hip/hip_runtime.h>

// S=1024 seq, B=32 batch, H=512 hid, E=512 emb, A=256 att — ALL f32
#define Sn 1024
#define Bn 32
#define Hn 512
#define En 512
#define An 256

// ============ proj: out[b][s][col] = scale*(X[r][:512].W[col][:512] + bias[col]), r=s*32+b
// Tiled GEMM: block = 64 rows x 256 cols (full N). 256 thr: tx=tid&63 (cols {tx+64j}),
// ty=tid>>6 (rows ty*16..+15). LDS staged transposed so global W reads are coalesced.
__global__ __launch_bounds__(256) void proj_gemm(const float* __restrict__ X,
                                                 const float* __restrict__ W,
                                                 const float* __restrict__ bias,
                                                 float* __restrict__ outp){
  __shared__ float Xs[16][64];    // [k][row]
  __shared__ float Ws[16][256];   // [k][col]
  int tid = threadIdx.x;
  int tx = tid & 63, ty = tid >> 6;
  long r0 = (long)blockIdx.x * 64;
  float acc[16][4];
  #pragma unroll
  for (int i = 0; i < 16; i++)
    #pragma unroll
    for (int j = 0; j < 4; j++) acc[i][j] = 0.f;

  int xrow = tid >> 2, xkg = (tid & 3) * 4;        // X stage: row, k-group
  for (int k0 = 0; k0 < 512; k0 += 16){
    __syncthreads();
    float4 xv = *(const float4*)&X[(r0 + xrow) * 512 + k0 + xkg];
    Xs[xkg + 0][xrow] = xv.x; Xs[xkg + 1][xrow] = xv.y;
    Xs[xkg + 2][xrow] = xv.z; Xs[xkg + 3][xrow] = xv.w;
    #pragma unroll
    for (int i = 0; i < 4; i++){
      int idx = i * 256 + tid;
      int n = idx >> 2, kg = (idx & 3) * 4;
      float4 wv = *(const float4*)&W[(long)n * 512 + k0 + kg];
      Ws[kg + 0][n] = wv.x; Ws[kg + 1][n] = wv.y;
      Ws[kg + 2][n] = wv.z; Ws[kg + 3][n] = wv.w;
    }
    __syncthreads();
    #pragma unroll
    for (int kk = 0; kk < 16; kk++){
      float4 x0 = *(const float4*)&Xs[kk][ty * 16];
      float4 x1 = *(const float4*)&Xs[kk][ty * 16 + 4];
      float4 x2 = *(const float4*)&Xs[kk][ty * 16 + 8];
      float4 x3 = *(const float4*)&Xs[kk][ty * 16 + 12];
      float xr[16] = {x0.x,x0.y,x0.z,x0.w, x1.x,x1.y,x1.z,x1.w,
                      x2.x,x2.y,x2.z,x2.w, x3.x,x3.y,x3.z,x3.w};
      float w0 = Ws[kk][tx], w1 = Ws[kk][tx + 64],
            w2 = Ws[kk][tx + 128], w3 = Ws[kk][tx + 192];
      #pragma unroll
      for (int i = 0; i < 16; i++){
        acc[i][0] += xr[i] * w0; acc[i][1] += xr[i] * w1;
        acc[i][2] += xr[i] * w2; acc[i][3] += xr[i] * w3;
      }
    }
  }
  const float scale = 2.8853900817779268f;  // 2*log2(e): pre-scale for exp2-based tanh
  float bz[4] = {bias[tx], bias[tx + 64], bias[tx + 128], bias[tx + 192]};
  #pragma unroll
  for (int i = 0; i < 16; i++){
    long r = r0 + ty * 16 + i;
    int b = (int)(r & 31), s = (int)(r >> 5);
    float* dst = outp + ((long)(b * Sn + s)) * An;
    #pragma unroll
    for (int j = 0; j < 4; j++)
      dst[tx + 64 * j] = (acc[i][j] + bz[j]) * scale;
  }
}

// ============ final: out[r][c] = X1[r][:].W1[c][:] + b1[c] + X2[r][:].W2[c][:] + b2[c]
// Block = 64 rows x full N=512 (full-N => block owns its rows; safe vs ctx aliasing out).
// Micro 16x8; cols {tx+64j}. Two K-phases (W1 then W2) share one 32KB Ws buffer.
__global__ __launch_bounds__(256) void final_gemm(const float* __restrict__ X1,
                                                  const float* __restrict__ X2,
                                                  const float* __restrict__ W1,
                                                  const float* __restrict__ b1,
                                                  const float* __restrict__ W2,
                                                  const float* __restrict__ b2,
                                                  float* __restrict__ outp){
  __shared__ float Xs[16][64];    // [k][row]
  __shared__ float Ws[16][512];   // [k][col] 32KB
  int tid = threadIdx.x;
  int tx = tid & 63, ty = tid >> 6;
  long r0 = (long)blockIdx.x * 64;
  float acc[16][8];
  #pragma unroll
  for (int i = 0; i < 16; i++)
    #pragma unroll
    for (int j = 0; j < 8; j++) acc[i][j] = 0.f;

  int xrow = tid >> 2, xkg = (tid & 3) * 4;
  for (int phase = 0; phase < 2; phase++){
    const float* Xp = phase ? X2 : X1;
    const float* Wp = phase ? W2 : W1;
    for (int k0 = 0; k0 < 512; k0 += 16){
      __syncthreads();
      float4 xv = *(const float4*)&Xp[(r0 + xrow) * 512 + k0 + xkg];
      Xs[xkg + 0][xrow] = xv.x; Xs[xkg + 1][xrow] = xv.y;
      Xs[xkg + 2][xrow] = xv.z; Xs[xkg + 3][xrow] = xv.w;
      #pragma unroll
      for (int i = 0; i < 8; i++){
        int idx = i * 256 + tid;
        int n = idx >> 2, kg = (idx & 3) * 4;
        float4 wv = *(const float4*)&Wp[(long)n * 512 + k0 + kg];
        Ws[kg + 0][n] = wv.x; Ws[kg + 1][n] = wv.y;
        Ws[kg + 2][n] = wv.z; Ws[kg + 3][n] = wv.w;
      }
      __syncthreads();
      #pragma unroll
      for (int kk = 0; kk < 16; kk++){
        float4 x0 = *(const float4*)&Xs[kk][ty * 16];
        float4 x1 = *(const float4*)&Xs[kk][ty * 16 + 4];
        float4 x2 = *(const float4*)&Xs[kk][ty * 16 + 8];
        float4 x3 = *(const float4*)&Xs[kk][ty * 16 + 12];
        float xr[16] = {x0.x,x0.y,x0.z,x0.w, x1.x,x1.y,x1.z,x1.w,
                        x2.x,x2.y,x2.z,x2.w, x3.x,x3.y,x3.z,x3.w};
        float wr[8];
        #pragma unroll
        for (int j = 0; j < 8; j++) wr[j] = Ws[kk][tx + 64 * j];
        #pragma unroll
        for (int i = 0; i < 16; i++)
          #pragma unroll
          for (int j = 0; j < 8; j++)
            acc[i][j] += xr[i] * wr[j];
      }
    }
  }
  float bz[8];
  #pragma unroll
  for (int j = 0; j < 8; j++) bz[j] = b1[tx + 64 * j] + b2[tx + 64 * j];
  #pragma unroll
  for (int i = 0; i < 16; i++){
    long r = r0 + ty * 16 + i;
    float* dst = outp + r * 512;
    #pragma unroll
    for (int j = 0; j < 8; j++)
      dst[tx + 64 * j] = acc[i][j] + bz[j];
  }
}

// ============ scores + softmax -> weights[q][k][b] f32 (straight to d_out) ============
__global__ __launch_bounds__(256) void score_kernel(const float* __restrict__ eat,
                                                    const float* __restrict__ pat,
                                                    const float* __restrict__ vptr,
                                                    float* __restrict__ wout){
  __shared__ float p[8][256];
  __shared__ float v2[256];
  __shared__ float sc[8][1024];
  int tid = threadIdx.x;
  int qt = gridDim.x - 1 - blockIdx.x;   // big-work tiles first
  int b = blockIdx.y;
  #pragma unroll
  for (int q = 0; q < 8; q++){
    int qg = qt * 8 + q;
    int t = qg > 0 ? qg - 1 : 0;
    p[q][tid] = pat[((long)(b * Sn + t)) * An + tid];
  }
  float vv = vptr[tid];
  v2[tid] = 2.0f * vv;
  sc[0][tid] = vv;          // block-local reduction for C = sum(v)
  __syncthreads();
  for (int off = 128; off; off >>= 1){
    if (tid < off) sc[0][tid] += sc[0][tid + off];
    __syncthreads();
  }
  float C = sc[0][0];
  __syncthreads();
  int Lmax = qt * 8 + 6; if (Lmax < 1) Lmax = 1;
  for (int ki = 0; ki * 256 < Lmax; ki++){
    int k = ki * 256 + tid;
    if (k < Lmax){
      const float4* ep = (const float4*)(eat + ((long)(b * Sn + k)) * An);
      float acc[8] = {0,0,0,0,0,0,0,0};
      for (int c = 0; c < 32; c++){
        float4 ea = ep[2*c], eb = ep[2*c + 1];
        float e[8] = {ea.x,ea.y,ea.z,ea.w,eb.x,eb.y,eb.z,eb.w};
        const float4* vp = (const float4*)&v2[c * 8];
        float4 va = vp[0], vb = vp[1];
        float vvv[8] = {va.x,va.y,va.z,va.w,vb.x,vb.y,vb.z,vb.w};
        #pragma unroll
        for (int q = 0; q < 8; q++){
          const float4* pp = (const float4*)&p[q][c * 8];
          float4 p0 = pp[0], p1 = pp[1];
          float pq[8] = {p0.x,p0.y,p0.z,p0.w,p1.x,p1.y,p1.z,p1.w};
          #pragma unroll
          for (int j = 0; j < 8; j++){
            // tanh(x) = 1 - 2/(exp(2x)+1); args pre-scaled by 2*log2(e).
            float t = __builtin_amdgcn_exp2f(pq[j] + e[j]);
            acc[q] += vvv[j] * __builtin_amdgcn_rcpf(t + 1.0f);
          }
        }
      }
      #pragma unroll
      for (int q = 0; q < 8; q++){
        int qg = qt * 8 + q;
        int L = qg - 1; if (L < 1) L = 1;
        sc[q][k] = (k < L) ? (C - acc[q]) : -1e30f;
      }
    }
  }
  __syncthreads();
  int g = tid >> 5, l = tid & 31;
  float m = -1e30f;
  for (int k = l; k < Lmax; k += 32) m = fmaxf(m, sc[g][k]);
  #pragma unroll
  for (int off = 16; off; off >>= 1) m = fmaxf(m, __shfl_xor(m, off, 32));
  const float LOG2E = 1.4426950408889634f;
  float ssum = 0.0f;
  for (int k = l; k < Lmax; k += 32){
    float e = __builtin_amdgcn_exp2f((sc[g][k] - m) * LOG2E);
    sc[g][k] = e; ssum += e;
  }
  #pragma unroll
  for (int off = 16; off; off >>= 1) ssum += __shfl_xor(ssum, off, 32);
  float rl = 1.0f / ssum;
  int qg = qt * 8 + g;
  // k >= Lmax stays zero from memset; k in [L, Lmax) writes exact 0 (exp underflow).
  for (int k = l; k < Lmax; k += 32)
    wout[((long)qg * Sn + k) * Bn + b] = sc[g][k] * rl;
}

// ============ context[q][b][e] = sum_k w[q][k][b] * emb[k][b][e] ============
// Block (qt,b): 32 queries, full E. Weights are BLOCK-UNIFORM -> scalar (SMEM) loads
// feeding v_fmac(v,s,v). No LDS. Zeros in w beyond L(q) handle the causal mask.
__global__ __launch_bounds__(256) void context_kernel(const float* __restrict__ w,
                                                      const float* __restrict__ emb,
                                                      float* __restrict__ ctx){
  int tid = threadIdx.x;
  int qt = gridDim.x - 1 - blockIdx.x;   // big-work tiles first
  int b = blockIdx.y;
  int q0 = qt * 32;
  int Lmax = q0 + 30; if (Lmax < 1) Lmax = 1;
  float acc[32][2];
  #pragma unroll
  for (int q = 0; q < 32; q++){ acc[q][0] = 0.f; acc[q][1] = 0.f; }
  for (int k0 = 0; k0 < Lmax; k0 += 8){
    float x0[8], x1[8];
    #pragma unroll
    for (int kk = 0; kk < 8; kk++){
      const float* er = emb + ((long)((k0 + kk) * Bn + b)) * En;
      x0[kk] = er[tid];
      x1[kk] = er[tid + 256];
    }
    #pragma unroll
    for (int q = 0; q < 32; q++){
      const float* wr = w + ((long)(q0 + q) * Sn + k0) * Bn + b;
      #pragma unroll
      for (int kk = 0; kk < 8; kk++){
        float wv = wr[kk * Bn];          // block-uniform -> s_load
        acc[q][0] += wv * x0[kk];
        acc[q][1] += wv * x1[kk];
      }
    }
  }
  #pragma unroll
  for (int q = 0; q < 32; q++){
    float* dst = ctx + ((long)((q0 + q) * Bn + b)) * En;
    dst[tid]       = acc[q][0];
    dst[tid + 256] = acc[q][1];
  }
}

extern "C" void kernel_launch(void* const* d_in, const int* in_sizes, int n_in,
                              void* d_out, int out_size, void* d_ws, size_t ws_size,
                              hipStream_t stream) {
  const float* outs  = (const float*)d_in[0];
  const float* emb   = (const float*)d_in[1];
  const float* W_enc = (const float*)d_in[2];
  const float* b_enc = (const float*)d_in[3];
  const float* W_dec = (const float*)d_in[4];
  const float* b_dec = (const float*)d_in[5];
  const float* v     = (const float*)d_in[6];
  const float* W_h2h = (const float*)d_in[7];
  const float* b_h2h = (const float*)d_in[8];
  const float* W_e2h = (const float*)d_in[9];
  const float* b_e2h = (const float*)d_in[10];

  float* out0 = (float*)d_out;                        // (S,B,H) = 16,777,216 f32
  float* outw = out0 + (size_t)Sn * Bn * Hn;          // (S,S,B) = 33,554,432 f32

  // No d_ws usage. Phase aliasing inside d_out's out0 region:
  //   phase 1: eat [b][k][a] at out0[0..8388608), pat [b][s][a] at out0[8388608..)
  //   phase 2 (after score): ctx [q*B+b][E] at out0[0..16777216)
  //   phase 3: final_gemm overwrites out0 (full-N blocks own their rows, no race)
  float* eat = out0;
  float* pat = out0 + (size_t)8388608;
  float* ctx = out0;

  hipMemsetAsync(outw, 0, (size_t)Sn * Sn * Bn * 4, stream);   // zero masked weights
  proj_gemm<<<512, 256, 0, stream>>>(emb,  W_enc, b_enc, eat);
  proj_gemm<<<512, 256, 0, stream>>>(outs, W_dec, b_dec, pat);
  score_kernel<<<dim3(128, 32), 256, 0, stream>>>(eat, pat, v, outw);
  context_kernel<<<dim3(32, 32), 256, 0, stream>>>(outw, emb, ctx);
  final_gemm<<<512, 256, 0, stream>>>(outs, ctx, W_h2h, b_h2h, W_e2h, b_e2h, out0);
}